// Round 1
// baseline (513.057 us; speedup 1.0000x reference)
//
#include <hip/hip_runtime.h>

// TGV prox primal-dual, 30 iterations on (3,512,512) fp32.
// Internal state in SoA planes (x2, r0, r1, u0..u3), ping-ponged in d_ws.
// Iter 1 specialized (state = (y,0,0)); iter 30 writes d_out in the reference
// interleaved layout. Per-block: 64x16 interior tile, u-planes staged to LDS
// with +2 halo, stage-1 (x/r prox -> xbar/rbar in LDS) on +1 ring, stage-2
// (u prox) on interior. Each thread owns a 4-wide float4 strip.
//
// This revision (latency-bound theory):
//  - all stage-1 global inputs (interior strip AND ring strip: y/x2/r0/r1)
//    are prefetched into registers BEFORE u-staging, so every global-load
//    latency in the kernel overlaps once instead of serializing per phase
//  - u-staging uses global_load_lds (async, no VGPR round trip) on fully
//    interior blocks; USTR=76 makes su contiguous so lds_off = 16*t matches
//    the wave-uniform-base + lane*16 DMA rule
//  - USTR 80->76 puts LDS at 39.9 KB; __launch_bounds__(256,3) guarantees
//    3 blocks/CU residency (VGPR <= 170)

#define H 512
#define W 512
#define C 3
#define HW (H * W)
#define CHW (C * H * W)
#define N_IT 30

#define TW 64
#define TH 16

#define TAU     0.01f
#define LAM2    0.15f
#define RHO     1.99f
#define SIGMA   1.3888888888888888f   /* 1/TAU/72 */
#define INV_TL1 1000.0f               /* 1/(TAU*LAM1) */
#define INV_1PT (1.0f / 1.01f)        /* 1/(1+TAU) */

// LDS geometry: u planes rows i0-2..i0+17 (20), cols j0-8..j0+67 staged (lc=gj-j0+8)
// USTR=76 exactly covers the 19 staged float4 chunks -> su is contiguous.
#define UROWS 20
#define USTR  76
// xbar/rbar planes rows -1..16 (18), cols lc = col+4 (col -4..67)
#define BROWS 18
#define BSTR  72

#define GLOAD_LDS16(g, l)                                    \
    __builtin_amdgcn_global_load_lds(                        \
        (const __attribute__((address_space(1))) void*)(g),  \
        (__attribute__((address_space(3))) void*)(l), 16, 0, 0)

template <int MODE> // 0 = first iter, 1 = middle, 2 = last (dst = d_out interleaved)
__global__ __launch_bounds__(256, 3)
void fused_it(const float* __restrict__ y,
              const float* __restrict__ src,
              float* __restrict__ dst)
{
    __shared__ __attribute__((aligned(16))) float su[4][UROWS][USTR];
    __shared__ __attribute__((aligned(16))) float sb[3][BROWS][BSTR]; // 0=xbar 1=rbar0 2=rbar1

    const int tid = threadIdx.x;
    const int c   = blockIdx.z;
    const int i0  = blockIdx.y * TH;
    const int j0  = blockIdx.x * TW;
    const int cb  = c * HW;

    const int ty = tid >> 4, tx = tid & 15;

    // ---- ring task mapping (tid < 68) ----
    int rr2 = 0, s2 = 0;
    const bool ring = tid < 68;
    if (ring) {
        if (tid < 18)      { rr2 = -1;       s2 = 4 * tid - 4; }
        else if (tid < 36) { rr2 = TH;       s2 = 4 * (tid - 18) - 4; }
        else if (tid < 52) { rr2 = tid - 36; s2 = -4; }
        else               { rr2 = tid - 52; s2 = TW; }
    }

    // ---- prefetch stage-1 global inputs into registers (issued BEFORE staging
    //      so all global latency in the kernel overlaps) ----
    auto load_strip = [&](int rr, int s, float* yv_, float* x2_, float* r0_, float* r1_) {
        const int gi  = i0 + rr;
        const int gjb = j0 + s;
        const bool row_ok = (unsigned)gi < H;
        if (row_ok && gjb >= 0 && gjb + 3 < W) {
            const int p = cb + gi * W + gjb;
            *(float4*)yv_ = *(const float4*)(y + p);
            if (MODE != 0) {
                *(float4*)x2_ = *(const float4*)(src + p);
                *(float4*)r0_ = *(const float4*)(src + CHW + p);
                *(float4*)r1_ = *(const float4*)(src + 2 * CHW + p);
            }
        } else {
            #pragma unroll
            for (int e = 0; e < 4; ++e) {
                const int gj = gjb + e;
                const bool ok = row_ok && ((unsigned)gj < W);
                const int p = cb + gi * W + gj;
                yv_[e] = ok ? y[p] : 0.f;
                if (MODE != 0) {
                    x2_[e] = ok ? src[p] : 0.f;
                    r0_[e] = ok ? src[CHW + p] : 0.f;
                    r1_[e] = ok ? src[2 * CHW + p] : 0.f;
                }
            }
        }
        if (MODE == 0) {
            #pragma unroll
            for (int e = 0; e < 4; ++e) { x2_[e] = yv_[e]; r0_[e] = 0.f; r1_[e] = 0.f; }
        }
    };

    float yv[4],  x2c[4],  r0c[4],  r1c[4];
    float yv2[4], x2c2[4], r0c2[4], r1c2[4];
    load_strip(ty, 4 * tx, yv, x2c, r0c, r1c);
    if (ring) load_strip(rr2, s2, yv2, x2c2, r0c2, r1c2);

    // ---- stage u planes into LDS ----
    if (MODE != 0) {
        const bool fastu = (blockIdx.y >= 1) && (blockIdx.y <= H / TH - 2) &&
                           (blockIdx.x >= 1) && (blockIdx.x <= W / TW - 2);
        if (fastu) {
            // all staged addresses in range: async DMA straight to LDS.
            // su is contiguous (4*20*76 floats); lds byte offset = 16*t.
            float* suf = &su[0][0][0];
            const float* ub = src + 3 * CHW + cb + (i0 - 2) * W + (j0 - 8);
            for (int t = tid; t < 4 * UROWS * 19; t += 256) {
                const int pl  = t / (UROWS * 19);
                const int rm  = t - pl * (UROWS * 19);
                const int row = rm / 19;
                const int k   = rm - row * 19;
                GLOAD_LDS16(ub + pl * CHW + row * W + 4 * k, suf + 4 * t);
            }
        } else {
            for (int t = tid; t < 4 * UROWS * 19; t += 256) {
                const int pl  = t / (UROWS * 19);
                const int rm  = t - pl * (UROWS * 19);
                const int row = rm / 19;
                const int k   = rm - row * 19;
                const int gi  = i0 + row - 2;
                const int gj  = j0 + 4 * k - 8;
                float4 v = make_float4(0.f, 0.f, 0.f, 0.f);
                if ((unsigned)gi < H) {
                    const float* p = src + (3 + pl) * CHW + cb + gi * W;
                    if (gj >= 0 && gj + 3 < W) {
                        v = *(const float4*)(p + gj);
                    } else {
                        float a0 = ((unsigned)(gj + 0) < W) ? p[gj + 0] : 0.f;
                        float a1 = ((unsigned)(gj + 1) < W) ? p[gj + 1] : 0.f;
                        float a2 = ((unsigned)(gj + 2) < W) ? p[gj + 2] : 0.f;
                        float a3 = ((unsigned)(gj + 3) < W) ? p[gj + 3] : 0.f;
                        v = make_float4(a0, a1, a2, a3);
                    }
                }
                *(float4*)&su[pl][row][4 * k] = v;
            }
        }
        __syncthreads();
    }

    // ---- stage 1: x/r prox on a strip of 4 positions; xbar/rbar -> LDS ----
    auto strip1 = [&](int rr, int s, bool interior,
                      const float* yv_, const float* x2_, const float* r0_, const float* r1_) {
        const int gi  = i0 + rr;
        const int gjb = j0 + s;

        float t0c[4], t1c[4], t0n[4], t1w[4];
        if (MODE == 0) {
            #pragma unroll
            for (int e = 0; e < 4; ++e) { t0c[e] = t1c[e] = t0n[e] = t1w[e] = 0.f; }
        } else {
            const int lr = rr + 2;
            const int lc = s + 8;
            float4 v;
            float u0n[4], u0c[4], u0s[4], u1n[5], u1c[5], u2r[6], u3n[5], u3c[5];
            v = *(const float4*)&su[0][lr - 1][lc]; u0n[0]=v.x; u0n[1]=v.y; u0n[2]=v.z; u0n[3]=v.w;
            v = *(const float4*)&su[0][lr    ][lc]; u0c[0]=v.x; u0c[1]=v.y; u0c[2]=v.z; u0c[3]=v.w;
            v = *(const float4*)&su[0][lr + 1][lc]; u0s[0]=v.x; u0s[1]=v.y; u0s[2]=v.z; u0s[3]=v.w;
            v = *(const float4*)&su[1][lr - 1][lc]; u1n[0]=v.x; u1n[1]=v.y; u1n[2]=v.z; u1n[3]=v.w;
            u1n[4] = su[1][lr - 1][lc + 4];
            v = *(const float4*)&su[1][lr    ][lc]; u1c[0]=v.x; u1c[1]=v.y; u1c[2]=v.z; u1c[3]=v.w;
            u1c[4] = su[1][lr][lc + 4];
            u2r[0] = su[2][lr][lc - 1];
            v = *(const float4*)&su[2][lr][lc]; u2r[1]=v.x; u2r[2]=v.y; u2r[3]=v.z; u2r[4]=v.w;
            u2r[5] = su[2][lr][lc + 4];
            u3n[0] = su[3][lr - 1][lc - 1];
            v = *(const float4*)&su[3][lr - 1][lc]; u3n[1]=v.x; u3n[2]=v.y; u3n[3]=v.z; u3n[4]=v.w;
            u3c[0] = su[3][lr][lc - 1];
            v = *(const float4*)&su[3][lr][lc]; u3c[1]=v.x; u3c[2]=v.y; u3c[3]=v.z; u3c[4]=v.w;

            const bool im0 = gi > 0, imHl = gi < H - 1;
            #pragma unroll
            for (int e = 0; e < 4; ++e) {
                const int gj = gjb + e;
                const bool jm0 = gj > 0;
                t0c[e] = TAU * (u0c[e] - u0s[e] + (jm0 ? u1c[e] : 0.f) - u1c[e + 1]);
                t1c[e] = TAU * (u2r[e + 1] - u2r[e + 2] + u3n[e + 1] - (imHl ? u3c[e + 1] : 0.f));
                t0n[e] = im0 ? TAU * (u0n[e] - u0c[e] + (jm0 ? u1n[e] : 0.f) - u1n[e + 1]) : 0.f;
                t1w[e] = jm0 ? TAU * (u2r[e] - u2r[e + 1] + u3n[e] - (imHl ? u3c[e] : 0.f)) : 0.f;
            }
        }

        const bool imH = gi < H - 1;
        float xnew[4], rn0[4], rn1[4], xb[4], rb0[4], rb1[4];
        #pragma unroll
        for (int e = 0; e < 4; ++e) {
            const int gj = gjb + e;
            const bool jmW = gj < W - 1;
            const float nT  = t0n[e] - (imH ? t0c[e] : 0.f) + t1w[e] - (jmW ? t1c[e] : 0.f);
            const float xv  = (x2_[e] - nT + TAU * yv_[e]) * INV_1PT;
            xb[e] = 2.f * xv - x2_[e];
            const float rp0 = r0_[e] + t0c[e];
            const float rp1 = r1_[e] + t1c[e];
            const float nrm = sqrtf(rp0 * rp0 + rp1 * rp1);
            const float f   = 1.f - 1.f / fmaxf(nrm * INV_TL1, 1.f);
            const float rv0 = rp0 * f, rv1 = rp1 * f;
            rb0[e]  = 2.f * rv0 - r0_[e];
            rb1[e]  = 2.f * rv1 - r1_[e];
            xnew[e] = x2_[e] + RHO * (xv - x2_[e]);
            rn0[e]  = r0_[e] + RHO * (rv0 - r0_[e]);
            rn1[e]  = r1_[e] + RHO * (rv1 - r1_[e]);
        }
        *(float4*)&sb[0][rr + 1][s + 4] = *(float4*)xb;
        *(float4*)&sb[1][rr + 1][s + 4] = *(float4*)rb0;
        *(float4*)&sb[2][rr + 1][s + 4] = *(float4*)rb1;

        if (interior) {
            const int p = cb + gi * W + gjb;
            if (MODE == 2) {
                *(float4*)(dst + p) = *(float4*)xnew;
                *(float4*)(dst + CHW + 2 * p)     = make_float4(rn0[0], rn1[0], rn0[1], rn1[1]);
                *(float4*)(dst + CHW + 2 * p + 4) = make_float4(rn0[2], rn1[2], rn0[3], rn1[3]);
            } else {
                *(float4*)(dst + p)           = *(float4*)xnew;
                *(float4*)(dst + CHW + p)     = *(float4*)rn0;
                *(float4*)(dst + 2 * CHW + p) = *(float4*)rn1;
            }
        }
    };

    // pass 1: interior 16 rows x 16 strips
    strip1(ty, 4 * tx, true, yv, x2c, r0c, r1c);
    // pass 2: +1 ring strips (prefetched inputs, no exposed global latency)
    if (ring) strip1(rr2, s2, false, yv2, x2c2, r0c2, r1c2);
    __syncthreads();

    // ---- stage 2: u prox on interior, xbar/rbar from LDS ----
    {
        const int gi  = i0 + ty;
        const int gjb = j0 + 4 * tx;
        const int lr  = ty + 1;
        const int lc  = 4 * tx + 4;
        float4 v;
        float xA[6], xS[6], xN[4], r0C[5], r0N[4], r1C[5], r1S[4];
        xA[0] = sb[0][lr][lc - 1];
        v = *(const float4*)&sb[0][lr][lc]; xA[1]=v.x; xA[2]=v.y; xA[3]=v.z; xA[4]=v.w;
        xA[5] = sb[0][lr][lc + 4];
        xS[0] = sb[0][lr + 1][lc - 1];
        v = *(const float4*)&sb[0][lr + 1][lc]; xS[1]=v.x; xS[2]=v.y; xS[3]=v.z; xS[4]=v.w;
        xS[5] = sb[0][lr + 1][lc + 4];
        v = *(const float4*)&sb[0][lr - 1][lc]; xN[0]=v.x; xN[1]=v.y; xN[2]=v.z; xN[3]=v.w;
        r0C[0] = sb[1][lr][lc - 1];
        v = *(const float4*)&sb[1][lr][lc]; r0C[1]=v.x; r0C[2]=v.y; r0C[3]=v.z; r0C[4]=v.w;
        v = *(const float4*)&sb[1][lr - 1][lc]; r0N[0]=v.x; r0N[1]=v.y; r0N[2]=v.z; r0N[3]=v.w;
        r1C[0] = sb[2][lr][lc - 1];
        v = *(const float4*)&sb[2][lr][lc]; r1C[1]=v.x; r1C[2]=v.y; r1C[3]=v.z; r1C[4]=v.w;
        v = *(const float4*)&sb[2][lr + 1][lc]; r1S[0]=v.x; r1S[1]=v.y; r1S[2]=v.z; r1S[3]=v.w;

        float u0o[4], u1o[4], u2o[4], u3o[4];
        if (MODE == 0) {
            #pragma unroll
            for (int e = 0; e < 4; ++e) { u0o[e] = u1o[e] = u2o[e] = u3o[e] = 0.f; }
        } else {
            const int lru = ty + 2, lcu = 4 * tx + 8;
            v = *(const float4*)&su[0][lru][lcu]; u0o[0]=v.x; u0o[1]=v.y; u0o[2]=v.z; u0o[3]=v.w;
            v = *(const float4*)&su[1][lru][lcu]; u1o[0]=v.x; u1o[1]=v.y; u1o[2]=v.z; u1o[3]=v.w;
            v = *(const float4*)&su[2][lru][lcu]; u2o[0]=v.x; u2o[1]=v.y; u2o[2]=v.z; u2o[3]=v.w;
            v = *(const float4*)&su[3][lru][lcu]; u3o[0]=v.x; u3o[1]=v.y; u3o[2]=v.z; u3o[3]=v.w;
        }

        const bool im0 = gi > 0, imH = gi < H - 1;
        float un0[4], un1[4], un2[4], un3[4];
        #pragma unroll
        for (int e = 0; e < 4; ++e) {
            const int gj = gjb + e;
            const bool jm0 = gj > 0, jmW = gj < W - 1;
            const float xC = xA[e + 1], xE = xA[e + 2], xW_ = xA[e];
            const float I0c = (imH ? xS[e + 1] - xC : 0.f) - r0C[e + 1];
            const float I0n = im0 ? (xC - xN[e] - r0N[e]) : 0.f;
            const float I0w = jm0 ? ((imH ? xS[e] - xW_ : 0.f) - r0C[e]) : 0.f;
            const float I1c = (jmW ? xE - xC : 0.f) - r1C[e + 1];
            const float I1w = jm0 ? (xC - xW_ - r1C[e]) : 0.f;
            const float I1s = imH ? ((jmW ? xS[e + 2] - xS[e + 1] : 0.f) - r1S[e]) : 0.f;
            const float g0 = I0c - I0n;
            const float g1 = jm0 ? (I0c - I0w) : 0.f;
            const float g2 = I1c - I1w;
            const float g3 = imH ? (I1s - I1c) : 0.f;
            const float up0 = u0o[e] + SIGMA * g0;
            const float up1 = u1o[e] + SIGMA * g1;
            const float up2 = u2o[e] + SIGMA * g2;
            const float up3 = u3o[e] + SIGMA * g3;
            const float nrm = sqrtf(up0 * up0 + up1 * up1 + up2 * up2 + up3 * up3);
            const float inv = 1.f / fmaxf(nrm * (1.0f / LAM2), 1.f);
            un0[e] = u0o[e] + RHO * (up0 * inv - u0o[e]);
            un1[e] = u1o[e] + RHO * (up1 * inv - u1o[e]);
            un2[e] = u2o[e] + RHO * (up2 * inv - u2o[e]);
            un3[e] = u3o[e] + RHO * (up3 * inv - u3o[e]);
        }
        const int p = cb + gi * W + gjb;
        if (MODE == 2) {
            #pragma unroll
            for (int e = 0; e < 4; ++e)
                *(float4*)(dst + 3 * CHW + 4 * (p + e)) =
                    make_float4(un0[e], un1[e], un2[e], un3[e]);
        } else {
            *(float4*)(dst + 3 * CHW + p) = *(float4*)un0;
            *(float4*)(dst + 4 * CHW + p) = *(float4*)un1;
            *(float4*)(dst + 5 * CHW + p) = *(float4*)un2;
            *(float4*)(dst + 6 * CHW + p) = *(float4*)un3;
        }
    }
}

extern "C" void kernel_launch(void* const* d_in, const int* in_sizes, int n_in,
                              void* d_out, int out_size, void* d_ws, size_t ws_size,
                              hipStream_t stream) {
    const float* y = (const float*)d_in[0];
    float* out  = (float*)d_out;
    float* buf0 = (float*)d_ws;
    float* buf1 = buf0 + 7 * CHW;   // 2 x 7 planes = 44 MB, ws is ~256 MB

    dim3 blk(256, 1, 1);
    dim3 grd(W / TW, H / TH, C);    // (8, 32, 3) = 768 blocks = 3/CU

    fused_it<0><<<grd, blk, 0, stream>>>(y, buf0 /*unused*/, buf0);
    for (int k = 2; k < N_IT; ++k) {
        float* s = (k % 2 == 0) ? buf0 : buf1;
        float* d = (k % 2 == 0) ? buf1 : buf0;
        fused_it<1><<<grd, blk, 0, stream>>>(y, s, d);
    }
    fused_it<2><<<grd, blk, 0, stream>>>(y, buf0, out);
}